// Round 13
// baseline (3641.528 us; speedup 1.0000x reference)
//
#include <hip/hip_runtime.h>
#include <cstddef>

#define B_  64
#define T_  256
#define I_  256
#define H_  1024
#define C_  1000
#define BH_ (B_ * H_)
#define SLOTS_ 16          // h history ring (>= fence period 8 + G0 - 1)

typedef _Float16 f16;
typedef __attribute__((ext_vector_type(8))) _Float16 f16x8;
typedef __attribute__((ext_vector_type(4))) float f32x4;

__device__ __forceinline__ float sigmoid_(float v) { return 1.0f / (1.0f + __expf(-v)); }
__device__ __forceinline__ float tanh_(float v) {
  float e = __expf(-2.0f * fabsf(v));
  float t = (1.0f - e) / (1.0f + e);
  return copysignf(t, v);
}

// h store: agent-scope relaxed atomic store, 8B (4 f16) per txn. Write-through,
// no dirty L2. R7 lesson: LOADS must stay cached.
__device__ __forceinline__ void storeH4(f16* p, float a, float b, float c, float d) {
  union { f16 h[4]; unsigned long long u; } pk;
  pk.h[0] = (f16)a; pk.h[1] = (f16)b; pk.h[2] = (f16)c; pk.h[3] = (f16)d;
  __hip_atomic_store((unsigned long long*)p, pk.u, __ATOMIC_RELAXED, __HIP_MEMORY_SCOPE_AGENT);
}

__device__ __forceinline__ void flag_add(unsigned* p) {
  __hip_atomic_fetch_add(p, 1u, __ATOMIC_RELAXED, __HIP_MEMORY_SCOPE_AGENT);
}

// R12 flag layout (u32 indices into the flags region, lines 128B apart):
//  F0c[t][mg][ch] : ((t*2+mg)*8+ch)*32      -- h0[t] chunk ch published (tgt 8)
//  F1c[t][mg][ch] : 131072 + same           -- h1[t] chunk ch published (tgt 8)
//  Ga [t][mg]     : 262144 + (t*2+mg)*32    -- h0[t] consumed (tgt 128)
//  Gb [t][mg]     : 278528 + (t*2+mg)*32    -- h1[t] consumed (tgt 64)
// 8 producers per chunk line -> the same-line RMW chain is 8 deep (was 64).

// One block = 512 threads = 8 waves = (K-split 4) x (N-split 2); 256 blocks,
// 1 block/CU. Block tile: 32 batch rows x 64 gate-cols. Per-wave weights in
// VGPRs, FULLY-unrolled prologue (R2 lesson: dynamic Wreg idx -> scratch).
// R12: per-wave chunk gating -- each wave waits only for the h k-chunks it
// reads (max over 8 producers, not 64), lane-parallel polls, ballot exit.
// Z-LDS double-buffered by phase parity since waves may be one phase apart.
template<bool IS_L1>
__device__ __forceinline__ void role_main(
    const f16* __restrict__ x16,
    const float* __restrict__ Wx, const float* __restrict__ Wh,
    const float* __restrict__ bias,
    f16* __restrict__ h0hist, f16* __restrict__ h1hist,
    unsigned* flags, int bid, int nslots,
    float* zbAll0, float* zbAll1, float* cLDS, float* biasLDS)
{
  constexpr int KTOT = IS_L1 ? 64 : 40;   // k-tiles of 32
  constexpr int NKT  = KTOT / 4;          // per-wave k-tiles (K-split over kq)
  constexpr int KX   = IS_L1 ? 1024 : 256;

  const int tid  = threadIdx.x;
  const int wv   = tid >> 6;          // 0..7
  const int nh   = wv >> 2;           // col-half (32 cols each)
  const int kq   = wv & 3;            // K quarter
  const int lane = tid & 63;
  const int c16  = lane & 15;
  const int quad = lane >> 4;
  const int rr7  = bid & 127;
  const int mgroup  = rr7 & 1;
  const int ubase   = (rr7 >> 1) * 16;
  const int rowbase = mgroup * 32;

  unsigned* F0c = flags;
  unsigned* F1c = flags + 131072;
  unsigned* Ga  = flags + 262144;
  unsigned* Gb  = flags + 278528;
  const int G0 = (nslots == 2) ? 2 : 8;
  const int G1 = (nslots == 2) ? 3 : 9;

  // per-wave chunk needs (8 chunks of 128 h-units each)
  const unsigned m0 = IS_L1 ? (kq == 0 ? 0x0Fu : kq == 1 ? 0xF0u : 0u)
                            : (kq == 0 ? 0x01u : kq == 1 ? 0x07u
                                              : kq == 2 ? 0x38u : 0xE0u);
  const unsigned m1 = IS_L1 ? (kq == 2 ? 0x0Fu : kq == 3 ? 0xF0u : 0u) : 0u;

  if (tid < 64) biasLDS[tid] = bias[(size_t)(tid >> 4) * H_ + ubase + (tid & 15)];
  cLDS[tid] = 0.0f;

  // ---- weight prologue: fp32 -> per-wave LDS panel -> f16 B-frags in VGPRs
  f16x8 Wreg[2][NKT];
  {
    f16* zpan = (f16*)zbAll0 + wv * 1024;   // private 2KB panel per wave
#pragma unroll
    for (int ii = 0; ii < NKT; ++ii) {
      const int kt = kq * NKT + ii;
#pragma unroll
      for (int rw = 0; rw < 16; ++rw) {
        const int krow  = rw * 2 + (lane >> 5);
        const int col32 = lane & 31;
        const int g = nh * 2 + (col32 >> 4);
        const int u = col32 & 15;
        const int k = kt * 32 + krow;
        float wval = (k < KX) ? Wx[((size_t)g * KX + k) * H_ + ubase + u]
                              : Wh[((size_t)g * H_ + (k - KX)) * H_ + ubase + u];
        zpan[krow * 32 + col32] = (f16)wval;
      }
#pragma unroll
      for (int nt = 0; nt < 2; ++nt) {
        f16x8 f;
#pragma unroll
        for (int j = 0; j < 8; ++j)
          f[j] = zpan[(quad * 8 + j) * 32 + nt * 16 + c16];  // B[n=lane&15][k=quad*8+j]
        Wreg[nt][ii] = f;
      }
    }
  }
  __syncthreads();

  const int ktbase = kq * NKT;
  const int row0 = rowbase + c16;

#pragma unroll 1
  for (int p = 0; p <= T_; ++p) {
    const bool active = IS_L1 ? (p >= 1) : (p < T_);
    if (active) {
      // ---- per-wave dataflow gate: lane-parallel chunk polls
      {
        unsigned* addr = nullptr; unsigned tgt = 0;
        if (lane < 8) {
          if (p >= 1 && ((m0 >> lane) & 1u))
            { addr = &F0c[(((p - 1) * 2 + mgroup) * 8 + lane) * 32]; tgt = 8; }
        } else if (lane < 16) {
          if (IS_L1 && p >= 2 && ((m1 >> (lane - 8)) & 1u))
            { addr = &F1c[(((p - 2) * 2 + mgroup) * 8 + (lane - 8)) * 32]; tgt = 8; }
        } else if (lane == 16) {
          if (!IS_L1 && p >= G0) { addr = &Ga[((p - G0) * 2 + mgroup) * 32]; tgt = 128; }
        } else if (lane == 17) {
          if (IS_L1 && p >= G1) { addr = &Gb[((p - G1) * 2 + mgroup) * 32]; tgt = 64; }
        }
        bool ok = (addr == nullptr);
        int g = 0;
        for (;;) {
          if (!ok)
            ok = __hip_atomic_load(addr, __ATOMIC_RELAXED, __HIP_MEMORY_SCOPE_AGENT) >= tgt;
          if (__ballot(ok) == ~0ull) break;
          if (++g > (1 << 17)) break;   // safety bail (uniform -> convergent)
          if (g < 16) __builtin_amdgcn_s_sleep(1);
          else        __builtin_amdgcn_s_sleep(8);
        }
        __builtin_amdgcn_fence(__ATOMIC_ACQUIRE, "wavefront");  // compiler order only
      }
      // every-8th-phase (or every phase in fallback) block-wide cache invalidate
      if ((nslots == 2) || ((p & 7) == 7)) {
        __syncthreads();
        if (tid == 0) __builtin_amdgcn_fence(__ATOMIC_ACQUIRE, "agent");
        __syncthreads();
      }

      const int sp  = p % nslots;
      const int spm = (p - 1 + nslots) % nslots;
      const int spp = (p + 1) % nslots;
      const f16* __restrict__ hA = h0hist + (size_t)sp * BH_;   // h0[p-1]
      const f16* __restrict__ hB = h1hist + (size_t)spm * BH_;  // h1[p-2]
      f16* __restrict__ hdst = IS_L1 ? (h1hist + (size_t)sp  * BH_)   // h1[p-1]
                                     : (h0hist + (size_t)spp * BH_);  // h0[p]

      // full-depth prefetch: all NKT x 2 loads issued before the MFMAs
      f16x8 Abuf[NKT][2];
#pragma unroll
      for (int ii = 0; ii < NKT; ++ii) {
        const int kt = ktbase + ii;
        const int k  = kt * 32 + quad * 8;
#pragma unroll
        for (int mt2 = 0; mt2 < 2; ++mt2) {
          const int row = row0 + mt2 * 16;
          if (!IS_L1 && k < 256) {          // x-part: immutable f16, cached
            Abuf[ii][mt2] = *(const f16x8*)(x16 + ((size_t)row * T_ + p) * I_ + k);
          } else if (IS_L1 && k >= 1024) {
            Abuf[ii][mt2] = *(const f16x8*)(hB + (size_t)row * H_ + (k - 1024));
          } else {
            const int kk = IS_L1 ? k : (k - 256);
            Abuf[ii][mt2] = *(const f16x8*)(hA + (size_t)row * H_ + kk);
          }
        }
      }

      f32x4 acc[2][2];
#pragma unroll
      for (int mt2 = 0; mt2 < 2; ++mt2)
#pragma unroll
        for (int nt = 0; nt < 2; ++nt)
          acc[mt2][nt] = (f32x4)0.0f;

#pragma unroll
      for (int i = 0; i < NKT; ++i) {
        const f16x8 a0 = Abuf[i][0];
        const f16x8 a1 = Abuf[i][1];
        acc[0][0] = __builtin_amdgcn_mfma_f32_16x16x32_f16(a0, Wreg[0][i], acc[0][0], 0, 0, 0);
        acc[0][1] = __builtin_amdgcn_mfma_f32_16x16x32_f16(a0, Wreg[1][i], acc[0][1], 0, 0, 0);
        acc[1][0] = __builtin_amdgcn_mfma_f32_16x16x32_f16(a1, Wreg[0][i], acc[1][0], 0, 0, 0);
        acc[1][1] = __builtin_amdgcn_mfma_f32_16x16x32_f16(a1, Wreg[1][i], acc[1][1], 0, 0, 0);
      }

      // partial z -> parity LDS buffer (waves may be one phase apart)
      float* zb = (p & 1) ? zbAll1 : zbAll0;
      float* zw = zb + (nh * 4 + kq) * 1024;
#pragma unroll
      for (int mt2 = 0; mt2 < 2; ++mt2)
#pragma unroll
        for (int nt = 0; nt < 2; ++nt)
#pragma unroll
          for (int e = 0; e < 4; ++e)
            zw[(mt2 * 2 + nt) * 256 + (quad * 4 + e) * 16 + c16] = acc[mt2][nt][e];

      __syncthreads();

      // consumers-done flags (A consumed by MFMA before the barrier)
      if (tid == 0) {
        if (p >= 1) flag_add(&Ga[((p - 1) * 2 + mgroup) * 32]);
        if (IS_L1 && p >= 2) flag_add(&Gb[((p - 2) * 2 + mgroup) * 32]);
      }

      // stage 1: reduce 4 K-partials + bias, in place into kq=0 region
      {
        const int base = tid * 4;          // 512 thr x 4 = 2048 final z
        const int nh1  = base >> 10;
        const int off  = base & 1023;
        f32x4 s = (f32x4)0.0f;
#pragma unroll
        for (int q = 0; q < 4; ++q)
          s += *(const f32x4*)(zb + nh1 * 4096 + q * 1024 + off);
        const int nt1 = (off >> 8) & 1;
        const int c0  = off & 15;
        s += *(const f32x4*)(biasLDS + (nh1 * 2 + nt1) * 16 + c0);
        *(f32x4*)(zb + nh1 * 4096 + off) = s;
      }
      __syncthreads();

      // stage 2: fused gates; c in LDS; h published via 8B write-through stores
      {
        const int row = tid >> 4, u = tid & 15;
        const int mt2 = row >> 4, r16 = row & 15;
        const float z0 = zb[0 * 4096 + (mt2 * 2 + 0) * 256 + r16 * 16 + u];
        const float z1 = zb[0 * 4096 + (mt2 * 2 + 1) * 256 + r16 * 16 + u];
        const float z2 = zb[1 * 4096 + (mt2 * 2 + 0) * 256 + r16 * 16 + u];
        const float z3 = zb[1 * 4096 + (mt2 * 2 + 1) * 256 + r16 * 16 + u];
        const float cv = cLDS[tid];
        const float gt = tanh_(z0);
        const float iv = sigmoid_(z1);
        const float fv = sigmoid_(z2);
        const float ov = sigmoid_(z3);
        const float cn = gt * iv + cv * fv;
        cLDS[tid] = cn;
        const float hn = tanh_(cn) * ov;
        const float h1v = __shfl_down(hn, 1);
        const float h2v = __shfl_down(hn, 2);
        const float h3v = __shfl_down(hn, 3);
        if ((u & 3) == 0)
          storeH4(hdst + (size_t)(rowbase + row) * H_ + ubase + u, hn, h1v, h2v, h3v);
      }
      __syncthreads();   // drain h stores (vmcnt) before publishing

      if (tid == 0) {
        const int ch = rr7 >> 4;    // this block's h chunk (8 producers/chunk)
        if (IS_L1) flag_add(&F1c[(((p - 1) * 2 + mgroup) * 8 + ch) * 32]);
        else       flag_add(&F0c[((p * 2 + mgroup) * 8 + ch) * 32]);
      }
    }
  }
}

__global__ __launch_bounds__(512, 1)
void lstm_persistent(const f16* __restrict__ x16,
                     const float* __restrict__ W0x, const float* __restrict__ W0h, const float* __restrict__ b0,
                     const float* __restrict__ W1x, const float* __restrict__ W1h, const float* __restrict__ b1,
                     f16* h0hist, f16* h1hist, unsigned* flags, int nslots)
{
  __shared__ float zbAll0[8192];   // 32KB: parity-0 partials / prologue panels
  __shared__ float zbAll1[8192];   // 32KB: parity-1 partials
  __shared__ float cLDS[512];
  __shared__ float biasLDS[64];
  const int bid = blockIdx.x;
  if (bid >= 128)
    role_main<true >(x16, W1x, W1h, b1, h0hist, h1hist, flags, bid, nslots, zbAll0, zbAll1, cLDS, biasLDS);
  else
    role_main<false>(x16, W0x, W0h, b0, h0hist, h1hist, flags, bid, nslots, zbAll0, zbAll1, cLDS, biasLDS);
}

// x fp32 -> f16, once
__global__ void cvt_x(const float* __restrict__ xin, f16* __restrict__ xo)
{
  const int i = (blockIdx.x * 256 + threadIdx.x) * 8;
  const float4 a = *(const float4*)(xin + i);
  const float4 b = *(const float4*)(xin + i + 4);
  f16x8 v;
  v[0] = (f16)a.x; v[1] = (f16)a.y; v[2] = (f16)a.z; v[3] = (f16)a.w;
  v[4] = (f16)b.x; v[5] = (f16)b.y; v[6] = (f16)b.z; v[7] = (f16)b.w;
  *(f16x8*)(xo + i) = v;
}

// out[b][c] = h1_final[b][:] . Wo[:][c] + bo[c]  (kernel-boundary acquire
// invalidates caches -> fresh h1 reads)
__global__ void out_gemm(const f16* __restrict__ h1,
                         const float* __restrict__ Wo, const float* __restrict__ bo,
                         float* __restrict__ out)
{
  __shared__ float ht[1024][8];
  const int tid = threadIdx.x;    // 128 threads
  const int b0r = blockIdx.y * 4;
  for (int i = tid; i < 4096; i += 128) {
    const int rr = i >> 10, k = i & 1023;
    ht[k][rr] = (float)h1[(size_t)(b0r + rr) * H_ + k];
  }
  __syncthreads();
  const int c = blockIdx.x * 125 + tid;
  if (tid < 125) {
    float a0 = 0.f, a1 = 0.f, a2 = 0.f, a3 = 0.f;
#pragma unroll 4
    for (int k = 0; k < 1024; ++k) {
      const float w = Wo[(size_t)k * C_ + c];
      a0 += ht[k][0] * w;
      a1 += ht[k][1] * w;
      a2 += ht[k][2] * w;
      a3 += ht[k][3] * w;
    }
    const float bb = bo[c];
    out[(size_t)(b0r + 0) * C_ + c] = a0 + bb;
    out[(size_t)(b0r + 1) * C_ + c] = a1 + bb;
    out[(size_t)(b0r + 2) * C_ + c] = a2 + bb;
    out[(size_t)(b0r + 3) * C_ + c] = a3 + bb;
  }
}

extern "C" void kernel_launch(void* const* d_in, const int* in_sizes, int n_in,
                              void* d_out, int out_size, void* d_ws, size_t ws_size,
                              hipStream_t stream)
{
  const float* x   = (const float*)d_in[0];
  const float* W0x = (const float*)d_in[1];
  const float* W0h = (const float*)d_in[2];
  const float* b0  = (const float*)d_in[3];
  const float* W1x = (const float*)d_in[4];
  const float* W1h = (const float*)d_in[5];
  const float* b1  = (const float*)d_in[6];
  const float* Wo  = (const float*)d_in[7];
  const float* bo  = (const float*)d_in[8];

  const size_t FLAGS_BYTES = 2u << 20;                               // 2 MB region
  const size_t xB = (size_t)B_ * T_ * I_ * sizeof(f16);              // 8 MB
  const size_t need16 = FLAGS_BYTES + (size_t)2 * SLOTS_ * BH_ * sizeof(f16) + xB;
  const int nslots = (ws_size >= need16) ? SLOTS_ : 2;
  const size_t histB = (size_t)nslots * BH_ * sizeof(f16);

  unsigned* flags = (unsigned*)d_ws;
  f16* h0hist = (f16*)((char*)d_ws + FLAGS_BYTES);
  f16* h1hist = (f16*)((char*)h0hist + histB);
  f16* x16    = (f16*)((char*)h1hist + histB);

  // zero: used flag arrays (1.125 MB) ; h0 slot0 ; h1 slot0
  hipMemsetAsync(d_ws, 0, 294912u * 4u, stream);
  hipMemsetAsync(h0hist, 0, (size_t)BH_ * sizeof(f16), stream);
  hipMemsetAsync(h1hist, 0, (size_t)BH_ * sizeof(f16), stream);

  hipLaunchKernelGGL(cvt_x, dim3((B_ * T_ * I_) / (256 * 8)), dim3(256), 0, stream, x, x16);

  hipLaunchKernelGGL(lstm_persistent, dim3(256), dim3(512), 0, stream,
                     x16, W0x, W0h, b0, W1x, W1h, b1, h0hist, h1hist, flags, nslots);

  // final h1 = h1[T-1], written at phase T -> slot T % nslots
  f16* h1fin = h1hist + (size_t)(T_ % nslots) * BH_;
  hipLaunchKernelGGL(out_gemm, dim3(8, 16), dim3(128), 0, stream,
                     h1fin, Wo, bo, (float*)d_out);
}